// Round 14
// baseline (1102.030 us; speedup 1.0000x reference)
//
#include <hip/hip_runtime.h>
#include <hip/hip_bf16.h>

// Block_ViT on MI355X — round 14: R12's proven single-buffer mfma2 + head-interleaved
// V2/P2 (ctx = one K=3840 GEMM per batch at 64-tile grid (C/64,13,4); softmax inlines
// rstd). Reverts R13's dbuf (guide m99/m100: neutral) and 128-tile ctx (grid collapse).
// B=4, N=784, H=4, Cs={64,128,256,512}, KV=960, NT=3136. fp32 in/out. ~102.0 MB ws.

using bf16 = __hip_bfloat16;
typedef __attribute__((ext_vector_type(8))) short short8;   // 8 bf16 (4 VGPRs)
typedef __attribute__((ext_vector_type(4))) float f32x4;    // MFMA acc

__device__ inline float bf2f(unsigned short u) {
    return __uint_as_float(((unsigned int)u) << 16);
}
__device__ inline unsigned short f2b(float f) {            // RTNE fp32->bf16
    unsigned int u = __float_as_uint(f);
    return (unsigned short)((u + 0x7fffu + ((u >> 16) & 1u)) >> 16);
}
__device__ inline float ld1f(const float* p) { return *p; }
__device__ inline float ld1f(const bf16* p) { return bf2f(*(const unsigned short*)p); }
__device__ inline void st1(float* p, float v) { *p = v; }
__device__ inline void st1(bf16* p, float v) { *((unsigned short*)p) = f2b(v); }
__device__ inline float4 ld4f(const bf16* p) {
    ushort4 u = *(const ushort4*)p;
    return make_float4(bf2f(u.x), bf2f(u.y), bf2f(u.z), bf2f(u.w));
}

// async global->LDS, 16 B per lane; LDS dest = wave-uniform base + lane*16
__device__ __forceinline__ void cp16(const void* g, void* l) {
    __builtin_amdgcn_global_load_lds(
        (const __attribute__((address_space(1))) void*)g,
        (__attribute__((address_space(3))) void*)l, 16, 0, 0);
}

// ---- block reductions (256 threads = 4 waves) ----
__device__ inline float blockSum256(float v, float* red) {
    #pragma unroll
    for (int o = 32; o > 0; o >>= 1) v += __shfl_down(v, o);
    int t = threadIdx.x;
    if ((t & 63) == 0) red[t >> 6] = v;
    __syncthreads();
    float r = red[0] + red[1] + red[2] + red[3];
    __syncthreads();
    return r;
}
__device__ inline float blockMax256(float v, float* red) {
    #pragma unroll
    for (int o = 32; o > 0; o >>= 1) v = fmaxf(v, __shfl_down(v, o));
    int t = threadIdx.x;
    if ((t & 63) == 0) red[t >> 6] = v;
    __syncthreads();
    float r = fmaxf(fmaxf(red[0], red[1]), fmaxf(red[2], red[3]));
    __syncthreads();
    return r;
}

// ---- fp32 -> bf16 weight conversion, up to 4 DISJOINT segments, grid-stride ----
struct Cvt4 {
    const float* s[4];
    unsigned short* d[4];
    long n[4];
};
__global__ __launch_bounds__(256)
void cvt_kernel(Cvt4 a) {
    long tid = (long)blockIdx.x * 256 + threadIdx.x;
    long stride = (long)gridDim.x * 256;
    for (int g = 0; g < 4; g++) {
        const float* s = a.s[g];
        if (!s) continue;
        unsigned short* d = a.d[g];
        long n = a.n[g];
        for (long i = tid * 4; i < n; i += stride * 4) {
            float4 v = *(const float4*)(s + i);
            *(ushort4*)(d + i) = make_ushort4(f2b(v.x), f2b(v.y), f2b(v.z), f2b(v.w));
        }
    }
}

// ==== MFMA NT GEMM, single-buffer m97 structure (R12-proven) ====
// C[z][M,N] = alpha*A[z]@B[z]^T (+bias)(+gelu)(+res); bf16 A/B, out CT.
// z-offsets: (z&3)*Xh + (z>>2)*Xb. TO: store C^T (bf16).
// 4 waves 2x2, wave tile (TM/2)x(TN/2), BK=32, LDS stride 32 shorts.
template <int TM, int TN, class CT, class RT, bool TO>
__global__ __launch_bounds__(256)
void mfma2(const bf16* __restrict__ A, long Ah, long Ab, int lda,
           const bf16* __restrict__ B, long Bh, long Bb, int ldb,
           CT* __restrict__ Cp, long Ch, long Cb, int ldc,
           const float* __restrict__ bias, const RT* __restrict__ res,
           int M, int N, int K, float alpha, int dogelu) {
    constexpr int MI = TM / 32, NI = TN / 32;
    __shared__ short As[TM * 32];
    __shared__ short Bs[TN * 32];
    int z = blockIdx.z;
    A += (long)(z & 3) * Ah + (long)(z >> 2) * Ab;
    B += (long)(z & 3) * Bh + (long)(z >> 2) * Bb;
    Cp += (long)(z & 3) * Ch + (long)(z >> 2) * Cb;
    int m0 = blockIdx.y * TM, n0 = blockIdx.x * TN;
    int t = threadIdx.x, lane = t & 63, wv = t >> 6;
    int col = lane & 15, quad = lane >> 4;
    int wm = wv >> 1, wn = wv & 1;
    f32x4 acc[MI][NI];
    #pragma unroll
    for (int i = 0; i < MI; i++)
        #pragma unroll
        for (int j = 0; j < NI; j++) acc[i][j] = (f32x4){0.f, 0.f, 0.f, 0.f};

    const bool fastblk = (m0 + TM <= M) && (n0 + TN <= N);
    int lrow = lane >> 2, lcol = (lane & 3) << 3;   // async per-lane row/col
    int sr = t >> 2, scs = (t & 3) << 3;            // manual path row/col

    for (int k0 = 0; k0 < K; k0 += 32) {
        if (fastblk && (k0 + 32 <= K)) {
            #pragma unroll
            for (int u = 0; u < TM / 64; u++) {
                int c = wv + 4 * u;
                int r = c * 16 + lrow;
                cp16(A + (long)(m0 + r) * lda + k0 + lcol, &As[c * 512]);
            }
            #pragma unroll
            for (int u = 0; u < TN / 64; u++) {
                int c = wv + 4 * u;
                int r = c * 16 + lrow;
                cp16(B + (long)(n0 + r) * ldb + k0 + lcol, &Bs[c * 512]);
            }
        } else {
            #pragma unroll
            for (int u = 0; u < TM / 64; u++) {
                int r = sr + u * 64;
                float4 v = make_float4(0.f, 0.f, 0.f, 0.f);
                if (m0 + r < M && k0 + scs < K)
                    v = *(const float4*)(A + (long)(m0 + r) * lda + k0 + scs);
                *(float4*)&As[r * 32 + scs] = v;
            }
            #pragma unroll
            for (int u = 0; u < TN / 64; u++) {
                int r = sr + u * 64;
                float4 v = make_float4(0.f, 0.f, 0.f, 0.f);
                if (n0 + r < N && k0 + scs < K)
                    v = *(const float4*)(B + (long)(n0 + r) * ldb + k0 + scs);
                *(float4*)&Bs[r * 32 + scs] = v;
            }
        }
        __syncthreads();
        short8 af[MI], bfr[NI];
        #pragma unroll
        for (int mi = 0; mi < MI; mi++)
            af[mi] = *(const short8*)&As[(wm * (TM / 2) + mi * 16 + col) * 32 + quad * 8];
        #pragma unroll
        for (int ni = 0; ni < NI; ni++)
            bfr[ni] = *(const short8*)&Bs[(wn * (TN / 2) + ni * 16 + col) * 32 + quad * 8];
        #pragma unroll
        for (int mi = 0; mi < MI; mi++)
            #pragma unroll
            for (int ni = 0; ni < NI; ni++)
                acc[mi][ni] = __builtin_amdgcn_mfma_f32_16x16x32_bf16(
                    af[mi], bfr[ni], acc[mi][ni], 0, 0, 0);
        __syncthreads();
    }
    // C/D layout: col=lane&15, row=quad*4+reg  [m89/m91]
    #pragma unroll
    for (int mi = 0; mi < MI; mi++) {
        int gmB = m0 + wm * (TM / 2) + mi * 16 + quad * 4;
        #pragma unroll
        for (int ni = 0; ni < NI; ni++) {
            int gn = n0 + wn * (TN / 2) + ni * 16 + col;
            if constexpr (TO) {
                if (gmB < M && gn < N) {
                    ushort4 w = make_ushort4(f2b(acc[mi][ni][0] * alpha),
                                             f2b(acc[mi][ni][1] * alpha),
                                             f2b(acc[mi][ni][2] * alpha),
                                             f2b(acc[mi][ni][3] * alpha));
                    *(ushort4*)((unsigned short*)Cp + (long)gn * ldc + gmB) = w;
                }
            } else {
                if (gn < N) {
                    float bz = bias ? bias[gn] : 0.f;
                    #pragma unroll
                    for (int r = 0; r < 4; r++) {
                        int gm = gmB + r;
                        if (gm < M) {
                            float v = acc[mi][ni][r] * alpha + bz;
                            if (dogelu) v = 0.5f * v * (1.f + erff(v * 0.70710678118f));
                            if (res) v += ld1f(res + (long)gm * ldc + gn);
                            st1(Cp + (long)gm * ldc + gn, v);
                        }
                    }
                }
            }
        }
    }
}

// ---- LayerNorm of concat: rows of [3136, 960] fp32 -> bf16 ----
__global__ __launch_bounds__(256)
void ln_concat_kernel(const float* __restrict__ e1, const float* __restrict__ e2,
                      const float* __restrict__ e3, const float* __restrict__ e4,
                      const float* __restrict__ g, const float* __restrict__ b,
                      bf16* __restrict__ ea) {
    __shared__ float x[960];
    __shared__ float red[4];
    long row = blockIdx.x;
    int t = threadIdx.x;
    const float* p1 = e1 + row * 64;
    const float* p2 = e2 + row * 128;
    const float* p3 = e3 + row * 256;
    const float* p4 = e4 + row * 512;
    for (int i = t; i < 64;  i += 256) x[i]       = p1[i];
    for (int i = t; i < 128; i += 256) x[64 + i]  = p2[i];
    for (int i = t; i < 256; i += 256) x[192 + i] = p3[i];
    for (int i = t; i < 512; i += 256) x[448 + i] = p4[i];
    __syncthreads();
    float s = 0.f, q = 0.f;
    for (int i = t; i < 960; i += 256) { float v = x[i]; s += v; q += v * v; }
    float S1 = blockSum256(s, red), S2 = blockSum256(q, red);
    const float inv = 1.f / 960.f;
    float mu = S1 * inv;
    float r = rsqrtf(S2 * inv - mu * mu + 1e-6f);
    for (int i = t; i < 960; i += 256)
        st1(ea + row * 960 + i, (x[i] - mu) * r * g[i] + b[i]);
}

// ---- batched first-LN of all 4 branches: grid (3136, 4) ----
struct LN4 {
    const float* x[4];
    const float* g[4];
    const float* b[4];
    bf16* y[4];
    int C[4];
};
__global__ __launch_bounds__(256)
void ln4_kernel(LN4 a) {
    __shared__ float x[512];
    __shared__ float red[4];
    int br = blockIdx.y;
    long row = blockIdx.x;
    int C = a.C[br];
    int t = threadIdx.x;
    const float* xr = a.x[br] + row * C;
    float s = 0.f, q = 0.f;
    for (int i = t; i < C; i += 256) { float v = xr[i]; x[i] = v; s += v; q += v * v; }
    float S1 = blockSum256(s, red), S2 = blockSum256(q, red);
    float mu = S1 / C;
    float r = rsqrtf(S2 / C - mu * mu + 1e-6f);
    const float* g = a.g[br];
    const float* b = a.b[br];
    bf16* y = a.y[br] + row * C;
    for (int i = t; i < C; i += 256) st1(y + i, (x[i] - mu) * r * g[i] + b[i]);
}

// ---- row LayerNorm (bf16 in) -> bf16 ----
__global__ __launch_bounds__(256)
void ln_rows_kernel(const bf16* __restrict__ X, const float* __restrict__ g,
                    const float* __restrict__ b, bf16* __restrict__ Y, int C) {
    __shared__ float x[512];
    __shared__ float red[4];
    long row = blockIdx.x;
    int t = threadIdx.x;
    const bf16* xr = X + row * C;
    float s = 0.f, q = 0.f;
    for (int i = t; i < C; i += 256) { float v = ld1f(xr + i); x[i] = v; s += v; q += v * v; }
    float S1 = blockSum256(s, red), S2 = blockSum256(q, red);
    float mu = S1 / C;
    float r = rsqrtf(S2 / C - mu * mu + 1e-6f);
    for (int i = t; i < C; i += 256)
        st1(Y + row * C + i, (x[i] - mu) * r * g[i] + b[i]);
}

// ---- instance-norm partial stats over interleaved P2[b][d][h][j] ----
// grid = 16 z * 16 parts; part p covers d in [p*C/16, (p+1)*C/16)
__global__ __launch_bounds__(256)
void inorm_part_kernel(const bf16* __restrict__ S, float2* __restrict__ part, int C) {
    __shared__ float red[4];
    int blk = blockIdx.x;
    int z = blk >> 4, p = blk & 15;
    int b = z >> 2, h = z & 3;
    int dn = C >> 4;
    int d0 = p * dn;
    float s = 0.f, q = 0.f;
    for (int d = d0; d < d0 + dn; d++) {
        const ushort4* row = (const ushort4*)((const unsigned short*)S +
                             (((long)(b * C + d) * 4 + h) * 960));
        for (int i = threadIdx.x; i < 240; i += 256) {
            ushort4 u = row[i];
            float a = bf2f(u.x), bb = bf2f(u.y), c = bf2f(u.z), dd = bf2f(u.w);
            s += a + bb + c + dd;
            q += a * a + bb * bb + c * c + dd * dd;
        }
    }
    float S1 = blockSum256(s, red), S2 = blockSum256(q, red);
    if (threadIdx.x == 0) part[blk] = make_float2(S1, S2);
}

// ---- softmax over j (960) on interleaved rows; rstd computed inline from parts ----
__global__ __launch_bounds__(256)
void softmax_kernel(bf16* __restrict__ S, const float2* __restrict__ part, int C) {
    __shared__ float x[960];
    __shared__ float red[4];
    long r = blockIdx.x;               // flat row = (b*C + d)*4 + h
    int t = threadIdx.x;
    int h = (int)(r & 3);
    int b = (int)((r >> 2) / C);
    int z = b * 4 + h;
    float s0 = 0.f, q0 = 0.f;
    #pragma unroll
    for (int j = 0; j < 16; j++) { float2 v = part[z * 16 + j]; s0 += v.x; q0 += v.y; }
    float n = (float)C * 960.f;
    float mu = s0 / n;
    float rs = rsqrtf(q0 / n - mu * mu + 1e-5f);
    bf16* row = S + r * 960;
    float mx = -3.4e38f;
    for (int i = t; i < 960; i += 256) {
        float v = ld1f(row + i) * rs; x[i] = v; mx = fmaxf(mx, v);
    }
    float M = blockMax256(mx, red);
    float s = 0.f;
    for (int i = t; i < 960; i += 256) { float e = __expf(x[i] - M); x[i] = e; s += e; }
    float Ssum = blockSum256(s, red);
    float inv = 1.f / Ssum;
    for (int i = t; i < 960; i += 256) st1(row + i, x[i] * inv);
}

extern "C" void kernel_launch(void* const* d_in, const int* in_sizes, int n_in,
                              void* d_out, int out_size, void* d_ws, size_t ws_size,
                              hipStream_t stream) {
    (void)in_sizes; (void)n_in; (void)out_size; (void)ws_size;
    const int Cs[4] = {64, 128, 256, 512};
    const float *emb[4], *ang[4], *anb[4], *Wq[4], *Wo[4], *fng[4], *fnb[4], *w1[4], *b1[4], *w2[4], *b2[4];
    for (int i = 0; i < 4; i++) {
        const int base = i * 11;
        emb[i] = (const float*)d_in[base + 0];
        ang[i] = (const float*)d_in[base + 1];
        anb[i] = (const float*)d_in[base + 2];
        Wq[i]  = (const float*)d_in[base + 3];
        Wo[i]  = (const float*)d_in[base + 4];
        fng[i] = (const float*)d_in[base + 5];
        fnb[i] = (const float*)d_in[base + 6];
        w1[i]  = (const float*)d_in[base + 7];
        b1[i]  = (const float*)d_in[base + 8];
        w2[i]  = (const float*)d_in[base + 9];
        b2[i]  = (const float*)d_in[base + 10];
    }
    const float* anAg = (const float*)d_in[44];
    const float* anAb = (const float*)d_in[45];
    const float* Wk   = (const float*)d_in[46];
    const float* Wv   = (const float*)d_in[47];

    const int NT = 3136;
    // ws layout (bytes), total ~102.0 MB (ws >= 102.2 MB confirmed R6)
    char* wsb = (char*)d_ws;
    bf16*   ea    = (bf16*)(wsb);                    // [3136,960]
    bf16*   KT    = (bf16*)(wsb + 6021120);          // [4][960][3136]
    bf16*   V2    = (bf16*)(wsb + 30105600);         // [3136][3840] head-interleaved
    bf16*   Qb    = (bf16*)(wsb + 54190080);         // QT [4][C][3136] / hid
    bf16*   P2    = (bf16*)(wsb + 67035136);         // [4][C][4][960]; wk/wv bf16 early
    bf16*   cxall = (bf16*)(wsb + 82763776);         // first-LN out, all branches
    bf16*   cxb   = (bf16*)(wsb + 88784896);         // ctx / post-res LN
    bf16*   xb    = (bf16*)(wsb + 91996160);         // residual
    bf16*   wtb   = (bf16*)(wsb + 95207424);         // per-branch weights (6.82 MB)
    float2* part  = (float2*)(wsb + 102023168);      // [256]
    bf16* wkb = P2;                 // P2 region free until branch-0 scores
    bf16* wvb = P2 + 3686400;
    const long cxoff[4] = {0, 64L * NT, 192L * NT, 448L * NT};

    float* out = (float*)d_out;
    const long ooff[4] = {0, 200704, 602112, 1404928};
    const float scale = 0.03227486121f;  // 1/sqrt(960)

    // Wk/Wv -> bf16 (disjoint targets)
    {
        Cvt4 a;
        a.s[0] = Wk; a.d[0] = (unsigned short*)wkb; a.n[0] = 3686400;
        a.s[1] = Wv; a.d[1] = (unsigned short*)wvb; a.n[1] = 3686400;
        a.s[2] = nullptr; a.s[3] = nullptr; a.d[2] = a.d[3] = nullptr; a.n[2] = a.n[3] = 0;
        cvt_kernel<<<512, 256, 0, stream>>>(a);
    }
    ln_concat_kernel<<<3136, 256, 0, stream>>>(emb[0], emb[1], emb[2], emb[3], anAg, anAb, ea);
    {
        LN4 a;
        for (int i = 0; i < 4; i++) {
            a.x[i] = emb[i]; a.g[i] = ang[i]; a.b[i] = anb[i];
            a.y[i] = cxall + cxoff[i]; a.C[i] = Cs[i];
        }
        ln4_kernel<<<dim3(3136, 4), 256, 0, stream>>>(a);
    }
    // KT[h] = (ea @ Wk[h]^T)^T
    mfma2<128, 128, bf16, float, true><<<dim3(8, 25, 4), 256, 0, stream>>>(
        ea, 0, 0, 960, wkb, 921600, 0, 960, KT, 3010560, 0, NT,
        nullptr, (const float*)nullptr, NT, 960, 960, 1.f, 0);
    // V2[token][h*960+j] = ea @ Wv[h]^T  (h-column offset via Ch=960, ldc=3840)
    mfma2<128, 128, bf16, float, false><<<dim3(8, 25, 4), 256, 0, stream>>>(
        ea, 0, 0, 960, wvb, 921600, 0, 960, V2, 960, 0, 3840,
        nullptr, (const float*)nullptr, NT, 960, 960, 1.f, 0);

    for (int i = 0; i < 4; i++) {
        const int C = Cs[i];
        const long C2 = (long)C * C;
        bf16* wqb = wtb;
        bf16* wob = wtb + 4 * C2;
        bf16* w1b = wtb + 5 * C2;
        bf16* w2b = wtb + 9 * C2;
        {
            Cvt4 a;
            a.s[0] = Wq[i]; a.d[0] = (unsigned short*)wqb; a.n[0] = 4 * C2;
            a.s[1] = Wo[i]; a.d[1] = (unsigned short*)wob; a.n[1] = C2;
            a.s[2] = w1[i]; a.d[2] = (unsigned short*)w1b; a.n[2] = 4 * C2;
            a.s[3] = w2[i]; a.d[3] = (unsigned short*)w2b; a.n[3] = 4 * C2;
            cvt_kernel<<<512, 256, 0, stream>>>(a);
        }
        // QT[h] = (cx @ Wq[h]^T)^T
        mfma2<64, 64, bf16, float, true><<<dim3(C / 64, 49, 4), 256, 0, stream>>>(
            cxall + cxoff[i], 0, 0, C, wqb, C2, 0, C, Qb, (long)C * NT, 0, NT,
            nullptr, (const float*)nullptr, NT, C, C, 1.f, 0);
        // P2[b][d][h][j] = scale * QT-slab @ KT-slab^T  (M=C, N=960, K=784)
        if (C >= 256)
            mfma2<128, 128, bf16, float, false><<<dim3(8, C / 128, 16), 256, 0, stream>>>(
                Qb, (long)C * NT, 784, NT, KT, 3010560, 784, NT,
                P2, 960, (long)C * 3840, 3840,
                nullptr, (const float*)nullptr, C, 960, 784, scale, 0);
        else
            mfma2<64, 64, bf16, float, false><<<dim3(15, C / 64, 16), 256, 0, stream>>>(
                Qb, (long)C * NT, 784, NT, KT, 3010560, 784, NT,
                P2, 960, (long)C * 3840, 3840,
                nullptr, (const float*)nullptr, C, 960, 784, scale, 0);
        // instance-norm partial stats + softmax (rstd inline)
        inorm_part_kernel<<<256, 256, 0, stream>>>(P2, part, C);
        softmax_kernel<<<16 * C, 256, 0, stream>>>(P2, part, C);
        // ctx[b][n][d] = 0.25 * V2-slab @ P2-slab^T  (M=784, N=C, K=3840), 64-tile
        mfma2<64, 64, bf16, float, false><<<dim3(C / 64, 13, 4), 256, 0, stream>>>(
            V2, 784L * 3840, 0, 3840, P2, (long)C * 3840, 0, 3840,
            cxb, 784L * C, 0, C,
            nullptr, (const float*)nullptr, 784, C, 3840, 0.25f, 0);
        // x = emb + ctx @ Wo^T  -> bf16
        mfma2<64, 64, bf16, float, false><<<dim3(C / 64, 49, 1), 256, 0, stream>>>(
            cxb, 0, 0, C, wob, 0, 0, C, xb, 0, 0, C,
            nullptr, emb[i], NT, C, C, 1.f, 0);
        // lnx = LN(x) -> bf16
        ln_rows_kernel<<<NT, 256, 0, stream>>>(xb, fng[i], fnb[i], cxb, C);
        // hid = gelu(lnx @ w1^T + b1) -> bf16
        if (C >= 256)
            mfma2<128, 128, bf16, float, false><<<dim3(4 * C / 128, 25, 1), 256, 0, stream>>>(
                cxb, 0, 0, C, w1b, 0, 0, C, Qb, 0, 0, 4 * C,
                b1[i], (const float*)nullptr, NT, 4 * C, C, 1.f, 1);
        else
            mfma2<64, 64, bf16, float, false><<<dim3(4 * C / 64, 49, 1), 256, 0, stream>>>(
                cxb, 0, 0, C, w1b, 0, 0, C, Qb, 0, 0, 4 * C,
                b1[i], (const float*)nullptr, NT, 4 * C, C, 1.f, 1);
        // out = x + hid @ w2^T + b2  (fp32 store to d_out)
        mfma2<64, 64, float, bf16, false><<<dim3(C / 64, 49, 1), 256, 0, stream>>>(
            Qb, 0, 0, 4 * C, w2b, 0, 0, 4 * C, out + ooff[i], 0, 0, C,
            b2[i], xb, NT, C, 4 * C, 1.f, 0);
    }
}

// Round 15
// 1017.420 us; speedup vs baseline: 1.0832x; 1.0832x over previous
//
#include <hip/hip_runtime.h>
#include <hip/hip_bf16.h>

// Block_ViT on MI355X — round 15: consolidation. Fused IN-stats in scores epilogue
// (R9 design, exonerated by R10/R11 bisection), merged KT+V2 projection dispatch,
// merged 5-way LN launch. Proven single-buffer mfma2 core. fp32 in/out. ~102.0 MB ws.
// B=4, N=784, H=4, Cs={64,128,256,512}, KV=960, NT=3136.

using bf16 = __hip_bfloat16;
typedef __attribute__((ext_vector_type(8))) short short8;   // 8 bf16 (4 VGPRs)
typedef __attribute__((ext_vector_type(4))) float f32x4;    // MFMA acc

__device__ inline float bf2f(unsigned short u) {
    return __uint_as_float(((unsigned int)u) << 16);
}
__device__ inline unsigned short f2b(float f) {            // RTNE fp32->bf16
    unsigned int u = __float_as_uint(f);
    return (unsigned short)((u + 0x7fffu + ((u >> 16) & 1u)) >> 16);
}
__device__ inline float ld1f(const float* p) { return *p; }
__device__ inline float ld1f(const bf16* p) { return bf2f(*(const unsigned short*)p); }
__device__ inline void st1(float* p, float v) { *p = v; }
__device__ inline void st1(bf16* p, float v) { *((unsigned short*)p) = f2b(v); }
__device__ inline float4 ld4f(const bf16* p) {
    ushort4 u = *(const ushort4*)p;
    return make_float4(bf2f(u.x), bf2f(u.y), bf2f(u.z), bf2f(u.w));
}

// async global->LDS, 16 B per lane; LDS dest = wave-uniform base + lane*16
__device__ __forceinline__ void cp16(const void* g, void* l) {
    __builtin_amdgcn_global_load_lds(
        (const __attribute__((address_space(1))) void*)g,
        (__attribute__((address_space(3))) void*)l, 16, 0, 0);
}

// ---- block reductions (256 threads = 4 waves) ----
__device__ inline float blockSum256(float v, float* red) {
    #pragma unroll
    for (int o = 32; o > 0; o >>= 1) v += __shfl_down(v, o);
    int t = threadIdx.x;
    if ((t & 63) == 0) red[t >> 6] = v;
    __syncthreads();
    float r = red[0] + red[1] + red[2] + red[3];
    __syncthreads();
    return r;
}
__device__ inline float blockMax256(float v, float* red) {
    #pragma unroll
    for (int o = 32; o > 0; o >>= 1) v = fmaxf(v, __shfl_down(v, o));
    int t = threadIdx.x;
    if ((t & 63) == 0) red[t >> 6] = v;
    __syncthreads();
    float r = fmaxf(fmaxf(red[0], red[1]), fmaxf(red[2], red[3]));
    __syncthreads();
    return r;
}

// ---- fp32 -> bf16 weight conversion, up to 4 DISJOINT segments, grid-stride ----
struct Cvt4 {
    const float* s[4];
    unsigned short* d[4];
    long n[4];
};
__global__ __launch_bounds__(256)
void cvt_kernel(Cvt4 a) {
    long tid = (long)blockIdx.x * 256 + threadIdx.x;
    long stride = (long)gridDim.x * 256;
    for (int g = 0; g < 4; g++) {
        const float* s = a.s[g];
        if (!s) continue;
        unsigned short* d = a.d[g];
        long n = a.n[g];
        for (long i = tid * 4; i < n; i += stride * 4) {
            float4 v = *(const float4*)(s + i);
            *(ushort4*)(d + i) = make_ushort4(f2b(v.x), f2b(v.y), f2b(v.z), f2b(v.w));
        }
    }
}

// ==== MFMA NT GEMM, single-buffer m97 structure ====
// MODE 0: normal store (+bias/gelu/res, optional fused IN stats into inpart[2z]).
// MODE 1: transposed bf16 store.
// MODE 2: KV-split — z<4: TO store into Cp (KT); z>=4: normal store into Cp2 (V2).
// z-offsets A/B: (z&3)*Xh + (z>>2)*Xb.
// 4 waves 2x2, wave tile (TM/2)x(TN/2), BK=32, LDS stride 32 shorts.
template <int TM, int TN, class CT, class RT, int MODE>
__global__ __launch_bounds__(256)
void mfma2(const bf16* __restrict__ A, long Ah, long Ab, int lda,
           const bf16* __restrict__ B, long Bh, long Bb, int ldb,
           CT* __restrict__ Cp, long Ch, long Cb, int ldc,
           CT* __restrict__ Cp2, long Ch2, int ldc2,
           const float* __restrict__ bias, const RT* __restrict__ res,
           float* __restrict__ inpart,
           int M, int N, int K, float alpha, int dogelu) {
    constexpr int MI = TM / 32, NI = TN / 32;
    __shared__ short As[TM * 32];
    __shared__ short Bs[TN * 32];
    __shared__ float redn[8];
    int z = blockIdx.z;
    A += (long)(z & 3) * Ah + (long)(z >> 2) * Ab;
    B += (long)(z & 3) * Bh + (long)(z >> 2) * Bb;
    CT* Co;
    int ldo;
    bool doTO;
    if constexpr (MODE == 2) {
        if (z < 4) { Co = Cp + (long)z * Ch; ldo = ldc; doTO = true; }
        else       { Co = Cp2 + (long)(z & 3) * Ch2; ldo = ldc2; doTO = false; }
    } else {
        Co = Cp + (long)(z & 3) * Ch + (long)(z >> 2) * Cb;
        ldo = ldc;
        doTO = (MODE == 1);
    }
    int m0 = blockIdx.y * TM, n0 = blockIdx.x * TN;
    int t = threadIdx.x, lane = t & 63, wv = t >> 6;
    int col = lane & 15, quad = lane >> 4;
    int wm = wv >> 1, wn = wv & 1;
    f32x4 acc[MI][NI];
    #pragma unroll
    for (int i = 0; i < MI; i++)
        #pragma unroll
        for (int j = 0; j < NI; j++) acc[i][j] = (f32x4){0.f, 0.f, 0.f, 0.f};

    const bool fastblk = (m0 + TM <= M) && (n0 + TN <= N);
    int lrow = lane >> 2, lcol = (lane & 3) << 3;   // async per-lane row/col
    int sr = t >> 2, scs = (t & 3) << 3;            // manual path row/col

    for (int k0 = 0; k0 < K; k0 += 32) {
        if (fastblk && (k0 + 32 <= K)) {
            #pragma unroll
            for (int u = 0; u < TM / 64; u++) {
                int c = wv + 4 * u;
                int r = c * 16 + lrow;
                cp16(A + (long)(m0 + r) * lda + k0 + lcol, &As[c * 512]);
            }
            #pragma unroll
            for (int u = 0; u < TN / 64; u++) {
                int c = wv + 4 * u;
                int r = c * 16 + lrow;
                cp16(B + (long)(n0 + r) * ldb + k0 + lcol, &Bs[c * 512]);
            }
        } else {
            #pragma unroll
            for (int u = 0; u < TM / 64; u++) {
                int r = sr + u * 64;
                float4 v = make_float4(0.f, 0.f, 0.f, 0.f);
                if (m0 + r < M && k0 + scs < K)
                    v = *(const float4*)(A + (long)(m0 + r) * lda + k0 + scs);
                *(float4*)&As[r * 32 + scs] = v;
            }
            #pragma unroll
            for (int u = 0; u < TN / 64; u++) {
                int r = sr + u * 64;
                float4 v = make_float4(0.f, 0.f, 0.f, 0.f);
                if (n0 + r < N && k0 + scs < K)
                    v = *(const float4*)(B + (long)(n0 + r) * ldb + k0 + scs);
                *(float4*)&Bs[r * 32 + scs] = v;
            }
        }
        __syncthreads();
        short8 af[MI], bfr[NI];
        #pragma unroll
        for (int mi = 0; mi < MI; mi++)
            af[mi] = *(const short8*)&As[(wm * (TM / 2) + mi * 16 + col) * 32 + quad * 8];
        #pragma unroll
        for (int ni = 0; ni < NI; ni++)
            bfr[ni] = *(const short8*)&Bs[(wn * (TN / 2) + ni * 16 + col) * 32 + quad * 8];
        #pragma unroll
        for (int mi = 0; mi < MI; mi++)
            #pragma unroll
            for (int ni = 0; ni < NI; ni++)
                acc[mi][ni] = __builtin_amdgcn_mfma_f32_16x16x32_bf16(
                    af[mi], bfr[ni], acc[mi][ni], 0, 0, 0);
        __syncthreads();
    }
    // C/D layout: col=lane&15, row=quad*4+reg  [m89/m91]
    float ps = 0.f, pq = 0.f;
    #pragma unroll
    for (int mi = 0; mi < MI; mi++) {
        int gmB = m0 + wm * (TM / 2) + mi * 16 + quad * 4;
        #pragma unroll
        for (int ni = 0; ni < NI; ni++) {
            int gn = n0 + wn * (TN / 2) + ni * 16 + col;
            if (doTO) {
                if (gmB < M && gn < N) {
                    ushort4 w = make_ushort4(f2b(acc[mi][ni][0] * alpha),
                                             f2b(acc[mi][ni][1] * alpha),
                                             f2b(acc[mi][ni][2] * alpha),
                                             f2b(acc[mi][ni][3] * alpha));
                    *(ushort4*)((unsigned short*)Co + (long)gn * ldo + gmB) = w;
                }
            } else {
                if (gn < N) {
                    float bz = (MODE == 0 && bias) ? bias[gn] : 0.f;
                    #pragma unroll
                    for (int r = 0; r < 4; r++) {
                        int gm = gmB + r;
                        if (gm < M) {
                            float v = acc[mi][ni][r] * alpha + bz;
                            if (MODE == 0 && dogelu)
                                v = 0.5f * v * (1.f + erff(v * 0.70710678118f));
                            if (MODE == 0 && inpart) { ps += v; pq += v * v; }
                            if (MODE == 0 && res) v += ld1f(res + (long)gm * ldo + gn);
                            st1(Co + (long)gm * ldo + gn, v);
                        }
                    }
                }
            }
        }
    }
    if (MODE == 0 && inpart) {   // fused instance-norm partial stats per z
        #pragma unroll
        for (int o = 32; o > 0; o >>= 1) {
            ps += __shfl_down(ps, o);
            pq += __shfl_down(pq, o);
        }
        if (lane == 0) { redn[wv * 2] = ps; redn[wv * 2 + 1] = pq; }
        __syncthreads();
        if (t == 0) {
            atomicAdd(&inpart[2 * z], redn[0] + redn[2] + redn[4] + redn[6]);
            atomicAdd(&inpart[2 * z + 1], redn[1] + redn[3] + redn[5] + redn[7]);
        }
    }
}

// ---- merged LN: grid (3136, 5). br<4: per-branch LN(emb)->cxall; br==4: LN(concat)->ea ----
struct LN5 {
    const float* e[4];
    const float* g[4];
    const float* b[4];
    bf16* y[4];
    int C[4];
    const float* cg;
    const float* cb;
    bf16* ea;
};
__global__ __launch_bounds__(256)
void ln5_kernel(LN5 a) {
    __shared__ float x[960];
    __shared__ float red[4];
    int br = blockIdx.y;
    long row = blockIdx.x;
    int t = threadIdx.x;
    if (br == 4) {
        const float* p1 = a.e[0] + row * 64;
        const float* p2 = a.e[1] + row * 128;
        const float* p3 = a.e[2] + row * 256;
        const float* p4 = a.e[3] + row * 512;
        for (int i = t; i < 64;  i += 256) x[i]       = p1[i];
        for (int i = t; i < 128; i += 256) x[64 + i]  = p2[i];
        for (int i = t; i < 256; i += 256) x[192 + i] = p3[i];
        for (int i = t; i < 512; i += 256) x[448 + i] = p4[i];
        __syncthreads();
        float s = 0.f, q = 0.f;
        for (int i = t; i < 960; i += 256) { float v = x[i]; s += v; q += v * v; }
        float S1 = blockSum256(s, red), S2 = blockSum256(q, red);
        float mu = S1 / 960.f;
        float r = rsqrtf(S2 / 960.f - mu * mu + 1e-6f);
        for (int i = t; i < 960; i += 256)
            st1(a.ea + row * 960 + i, (x[i] - mu) * r * a.cg[i] + a.cb[i]);
    } else {
        int C = a.C[br];
        const float* xr = a.e[br] + row * C;
        float s = 0.f, q = 0.f;
        for (int i = t; i < C; i += 256) { float v = xr[i]; x[i] = v; s += v; q += v * v; }
        float S1 = blockSum256(s, red), S2 = blockSum256(q, red);
        float mu = S1 / C;
        float r = rsqrtf(S2 / C - mu * mu + 1e-6f);
        const float* g = a.g[br];
        const float* b = a.b[br];
        bf16* y = a.y[br] + row * C;
        for (int i = t; i < C; i += 256) st1(y + i, (x[i] - mu) * r * g[i] + b[i]);
    }
}

// ---- row LayerNorm (bf16 in) -> bf16 ----
__global__ __launch_bounds__(256)
void ln_rows_kernel(const bf16* __restrict__ X, const float* __restrict__ g,
                    const float* __restrict__ b, bf16* __restrict__ Y, int C) {
    __shared__ float x[512];
    __shared__ float red[4];
    long row = blockIdx.x;
    int t = threadIdx.x;
    const bf16* xr = X + row * C;
    float s = 0.f, q = 0.f;
    for (int i = t; i < C; i += 256) { float v = ld1f(xr + i); x[i] = v; s += v; q += v * v; }
    float S1 = blockSum256(s, red), S2 = blockSum256(q, red);
    float mu = S1 / C;
    float r = rsqrtf(S2 / C - mu * mu + 1e-6f);
    for (int i = t; i < C; i += 256)
        st1(Y + row * C + i, (x[i] - mu) * r * g[i] + b[i]);
}

// ---- softmax over j (960) on interleaved rows; rstd inline from fused stats ----
__global__ __launch_bounds__(256)
void softmax_kernel(bf16* __restrict__ S, const float* __restrict__ part, int C) {
    __shared__ float x[960];
    __shared__ float red[4];
    long r = blockIdx.x;               // flat row = (b*C + d)*4 + h
    int t = threadIdx.x;
    int h = (int)(r & 3);
    int b = (int)((r >> 2) / C);
    int z = b * 4 + h;
    float n = (float)C * 960.f;
    float mu = part[2 * z] / n;
    float rs = rsqrtf(part[2 * z + 1] / n - mu * mu + 1e-5f);
    bf16* row = S + r * 960;
    float mx = -3.4e38f;
    for (int i = t; i < 960; i += 256) {
        float v = ld1f(row + i) * rs; x[i] = v; mx = fmaxf(mx, v);
    }
    float M = blockMax256(mx, red);
    float s = 0.f;
    for (int i = t; i < 960; i += 256) { float e = __expf(x[i] - M); x[i] = e; s += e; }
    float Ssum = blockSum256(s, red);
    float inv = 1.f / Ssum;
    for (int i = t; i < 960; i += 256) st1(row + i, x[i] * inv);
}

extern "C" void kernel_launch(void* const* d_in, const int* in_sizes, int n_in,
                              void* d_out, int out_size, void* d_ws, size_t ws_size,
                              hipStream_t stream) {
    (void)in_sizes; (void)n_in; (void)out_size; (void)ws_size;
    const int Cs[4] = {64, 128, 256, 512};
    const float *emb[4], *ang[4], *anb[4], *Wq[4], *Wo[4], *fng[4], *fnb[4], *w1[4], *b1[4], *w2[4], *b2[4];
    for (int i = 0; i < 4; i++) {
        const int base = i * 11;
        emb[i] = (const float*)d_in[base + 0];
        ang[i] = (const float*)d_in[base + 1];
        anb[i] = (const float*)d_in[base + 2];
        Wq[i]  = (const float*)d_in[base + 3];
        Wo[i]  = (const float*)d_in[base + 4];
        fng[i] = (const float*)d_in[base + 5];
        fnb[i] = (const float*)d_in[base + 6];
        w1[i]  = (const float*)d_in[base + 7];
        b1[i]  = (const float*)d_in[base + 8];
        w2[i]  = (const float*)d_in[base + 9];
        b2[i]  = (const float*)d_in[base + 10];
    }
    const float* anAg = (const float*)d_in[44];
    const float* anAb = (const float*)d_in[45];
    const float* Wk   = (const float*)d_in[46];
    const float* Wv   = (const float*)d_in[47];

    const int NT = 3136;
    // ws layout (bytes), total ~102.0 MB (ws >= 102.2 MB confirmed R6)
    char* wsb = (char*)d_ws;
    bf16*  ea    = (bf16*)(wsb);                    // [3136,960]
    bf16*  KT    = (bf16*)(wsb + 6021120);          // [4][960][3136]
    bf16*  V2    = (bf16*)(wsb + 30105600);         // [3136][3840] head-interleaved
    bf16*  Qb    = (bf16*)(wsb + 54190080);         // QT [4][C][3136] / hid
    bf16*  P2    = (bf16*)(wsb + 67035136);         // [4][C][4][960]; wk/wv bf16 early
    bf16*  cxall = (bf16*)(wsb + 82763776);         // first-LN out, all branches
    bf16*  cxb   = (bf16*)(wsb + 88784896);         // ctx / post-res LN
    bf16*  xb    = (bf16*)(wsb + 91996160);         // residual
    bf16*  wtb   = (bf16*)(wsb + 95207424);         // per-branch weights (6.82 MB)
    float* partA = (float*)(wsb + 102023168);       // [4][16][2]
    bf16* wkb = P2;                 // P2 region free until branch-0 scores
    bf16* wvb = P2 + 3686400;
    const long cxoff[4] = {0, 64L * NT, 192L * NT, 448L * NT};

    float* out = (float*)d_out;
    const long ooff[4] = {0, 200704, 602112, 1404928};
    const float scale = 0.03227486121f;  // 1/sqrt(960)

    hipMemsetAsync(partA, 0, 4 * 16 * 2 * sizeof(float), stream);

    // Wk/Wv -> bf16 (disjoint targets)
    {
        Cvt4 a;
        a.s[0] = Wk; a.d[0] = (unsigned short*)wkb; a.n[0] = 3686400;
        a.s[1] = Wv; a.d[1] = (unsigned short*)wvb; a.n[1] = 3686400;
        a.s[2] = nullptr; a.s[3] = nullptr; a.d[2] = a.d[3] = nullptr; a.n[2] = a.n[3] = 0;
        cvt_kernel<<<512, 256, 0, stream>>>(a);
    }
    // merged 5-way LN (4 branch LNs + concat LN)
    {
        LN5 a;
        for (int i = 0; i < 4; i++) {
            a.e[i] = emb[i]; a.g[i] = ang[i]; a.b[i] = anb[i];
            a.y[i] = cxall + cxoff[i]; a.C[i] = Cs[i];
        }
        a.cg = anAg; a.cb = anAb; a.ea = ea;
        ln5_kernel<<<dim3(3136, 5), 256, 0, stream>>>(a);
    }
    // merged K/V projection: z=0..3 -> KT (TO), z=4..7 -> V2 (head-interleaved)
    mfma2<128, 128, bf16, float, 2><<<dim3(8, 25, 8), 256, 0, stream>>>(
        ea, 0, 0, 960, wkb, 921600, 3686400, 960,
        KT, 3010560, 0, NT, V2, 960, 3840,
        nullptr, (const float*)nullptr, nullptr, NT, 960, 960, 1.f, 0);

    for (int i = 0; i < 4; i++) {
        const int C = Cs[i];
        const long C2 = (long)C * C;
        bf16* wqb = wtb;
        bf16* wob = wtb + 4 * C2;
        bf16* w1b = wtb + 5 * C2;
        bf16* w2b = wtb + 9 * C2;
        float* part = partA + i * 32;
        {
            Cvt4 a;
            a.s[0] = Wq[i]; a.d[0] = (unsigned short*)wqb; a.n[0] = 4 * C2;
            a.s[1] = Wo[i]; a.d[1] = (unsigned short*)wob; a.n[1] = C2;
            a.s[2] = w1[i]; a.d[2] = (unsigned short*)w1b; a.n[2] = 4 * C2;
            a.s[3] = w2[i]; a.d[3] = (unsigned short*)w2b; a.n[3] = 4 * C2;
            cvt_kernel<<<512, 256, 0, stream>>>(a);
        }
        // QT[h] = (cx @ Wq[h]^T)^T
        mfma2<64, 64, bf16, float, 1><<<dim3(C / 64, 49, 4), 256, 0, stream>>>(
            cxall + cxoff[i], 0, 0, C, wqb, C2, 0, C, Qb, (long)C * NT, 0, NT,
            (bf16*)nullptr, 0, 0,
            nullptr, (const float*)nullptr, nullptr, NT, C, C, 1.f, 0);
        // P2[b][d][h][j] = scale * QT-slab @ KT-slab^T  (M=C, N=960, K=784) + fused stats
        if (C >= 256)
            mfma2<128, 128, bf16, float, 0><<<dim3(8, C / 128, 16), 256, 0, stream>>>(
                Qb, (long)C * NT, 784, NT, KT, 3010560, 784, NT,
                P2, 960, (long)C * 3840, 3840, (bf16*)nullptr, 0, 0,
                nullptr, (const float*)nullptr, part, C, 960, 784, scale, 0);
        else
            mfma2<64, 64, bf16, float, 0><<<dim3(15, C / 64, 16), 256, 0, stream>>>(
                Qb, (long)C * NT, 784, NT, KT, 3010560, 784, NT,
                P2, 960, (long)C * 3840, 3840, (bf16*)nullptr, 0, 0,
                nullptr, (const float*)nullptr, part, C, 960, 784, scale, 0);
        // softmax (rstd inline from fused stats)
        softmax_kernel<<<16 * C, 256, 0, stream>>>(P2, part, C);
        // ctx[b][n][d] = 0.25 * V2-slab @ P2-slab^T  (M=784, N=C, K=3840), 64-tile
        mfma2<64, 64, bf16, float, 0><<<dim3(C / 64, 13, 4), 256, 0, stream>>>(
            V2, 784L * 3840, 0, 3840, P2, (long)C * 3840, 0, 3840,
            cxb, 784L * C, 0, C, (bf16*)nullptr, 0, 0,
            nullptr, (const float*)nullptr, nullptr, 784, C, 3840, 0.25f, 0);
        // x = emb + ctx @ Wo^T  -> bf16
        mfma2<64, 64, bf16, float, 0><<<dim3(C / 64, 49, 1), 256, 0, stream>>>(
            cxb, 0, 0, C, wob, 0, 0, C, xb, 0, 0, C, (bf16*)nullptr, 0, 0,
            nullptr, emb[i], nullptr, NT, C, C, 1.f, 0);
        // lnx = LN(x) -> bf16
        ln_rows_kernel<<<NT, 256, 0, stream>>>(xb, fng[i], fnb[i], cxb, C);
        // hid = gelu(lnx @ w1^T + b1) -> bf16
        if (C >= 256)
            mfma2<128, 128, bf16, float, 0><<<dim3(4 * C / 128, 25, 1), 256, 0, stream>>>(
                cxb, 0, 0, C, w1b, 0, 0, C, Qb, 0, 0, 4 * C, (bf16*)nullptr, 0, 0,
                b1[i], (const float*)nullptr, nullptr, NT, 4 * C, C, 1.f, 1);
        else
            mfma2<64, 64, bf16, float, 0><<<dim3(4 * C / 64, 49, 1), 256, 0, stream>>>(
                cxb, 0, 0, C, w1b, 0, 0, C, Qb, 0, 0, 4 * C, (bf16*)nullptr, 0, 0,
                b1[i], (const float*)nullptr, nullptr, NT, 4 * C, C, 1.f, 1);
        // out = x + hid @ w2^T + b2  (fp32 store to d_out)
        mfma2<64, 64, float, bf16, 0><<<dim3(C / 64, 49, 1), 256, 0, stream>>>(
            Qb, 0, 0, 4 * C, w2b, 0, 0, 4 * C, out + ooff[i], 0, 0, C, (float*)nullptr, 0, 0,
            b2[i], xb, nullptr, NT, C, 4 * C, 1.f, 0);
    }
}